// Round 1
// baseline (644.169 us; speedup 1.0000x reference)
//
#include <hip/hip_runtime.h>
#include <hip/hip_bf16.h>
#include <math.h>

#define NNODES 100000
#define NEDGES 800000
#define HDIM 64
#define CDIM 10
#define NLAYERS 3
#define NGRAPH 500
#define CAP 40
#define OVFCAP 4096
#define BN_EPS 1e-5f

// ---------------- CSR build (bucketed, fixed capacity + overflow list) ----------------
__global__ void fill_buckets(const int* __restrict__ src, const int* __restrict__ dst,
                             unsigned* __restrict__ cnt, int* __restrict__ csr,
                             unsigned* __restrict__ ovfcnt, int* __restrict__ ovf) {
    int e = blockIdx.x * blockDim.x + threadIdx.x;
    if (e >= NEDGES) return;
    int d = dst[e];
    unsigned slot = atomicAdd(&cnt[d], 1u);
    if (slot < CAP) {
        csr[(size_t)d * CAP + slot] = src[e];
    } else {
        unsigned o = atomicAdd(ovfcnt, 1u);
        if (o < OVFCAP) { ovf[2*o] = src[e]; ovf[2*o+1] = d; }
    }
}

// ---------------- gather-based aggregation: wave per node, lane per feature ----------
__global__ void aggregate(const float* __restrict__ hin, const unsigned* __restrict__ cnt,
                          const int* __restrict__ csr, float* __restrict__ M) {
    int node = blockIdx.x * 4 + (threadIdx.x >> 6);
    int lane = threadIdx.x & 63;
    unsigned deg = cnt[node]; if (deg > CAP) deg = CAP;
    const int* lst = csr + (size_t)node * CAP;
    float acc = 0.f;
    for (unsigned e = 0; e < deg; ++e) {
        int s = lst[e];                     // lane-uniform broadcast load
        acc += hin[(size_t)s * HDIM + lane];  // coalesced 256B row
    }
    M[(size_t)node * HDIM + lane] = acc;
}

// overflow edges (should be zero, but correctness-safe)
__global__ void ovf_add(const float* __restrict__ hin, const unsigned* __restrict__ ovfcnt,
                        const int* __restrict__ ovf, float* __restrict__ M) {
    unsigned n = *ovfcnt; if (n > OVFCAP) n = OVFCAP;
    unsigned total = n * HDIM;
    for (unsigned t = threadIdx.x; t < total; t += blockDim.x) {
        unsigned o = t >> 6; int j = t & 63;
        int s = ovf[2*o], d = ovf[2*o+1];
        atomicAdd(&M[(size_t)d*HDIM + j], hin[(size_t)s*HDIM + j]);
    }
}

// ---------------- fallback: pure atomic scatter (if ws too small for CSR) -----------
__global__ void scatter_atomic(const float* __restrict__ hin, const int* __restrict__ src,
                               const int* __restrict__ dst, float* __restrict__ M) {
    long long t = (long long)blockIdx.x * blockDim.x + threadIdx.x;
    if (t >= (long long)NEDGES * HDIM) return;
    int e = (int)(t >> 6), j = (int)(t & 63);
    atomicAdd(&M[(size_t)dst[e]*HDIM + j], hin[(size_t)src[e]*HDIM + j]);
}

// ---------------- linear + BN + ELU: wave per node, W in LDS ------------------------
__global__ void transform(const float* __restrict__ M, float* __restrict__ hout,
                          const float* __restrict__ Ws, const float* __restrict__ bs,
                          const float* __restrict__ gammas, const float* __restrict__ betas,
                          const float* __restrict__ means, const float* __restrict__ vars_,
                          int layer) {
    __shared__ float Wlds[HDIM*HDIM];
    int tid = threadIdx.x;
    const float4* Wg = (const float4*)(Ws + (size_t)layer*HDIM*HDIM);
    float4* Wl4 = (float4*)Wlds;
    #pragma unroll
    for (int r = 0; r < 4; ++r) Wl4[tid + r*256] = Wg[tid + r*256];
    __syncthreads();

    int node = blockIdx.x*4 + (tid >> 6);
    int j = tid & 63;
    float mval = M[(size_t)node*HDIM + j];
    float acc = 0.f;
    #pragma unroll
    for (int k = 0; k < HDIM; ++k)
        acc += __shfl(mval, k, 64) * Wlds[k*HDIM + j];

    float b  = bs[layer*HDIM + j];
    float g  = gammas[layer*HDIM + j];
    float be = betas[layer*HDIM + j];
    float mu = means[layer*HDIM + j];
    float vv = vars_[layer*HDIM + j];
    float scale = g * rsqrtf(vv + BN_EPS);
    float y = (acc + b - mu) * scale + be;
    hout[(size_t)node*HDIM + j] = (y > 0.f) ? y : expm1f(y);
}

// ---------------- logits -> entropy per node + global max ---------------------------
__global__ void classify(const float* __restrict__ H, const float* __restrict__ Wc,
                         const float* __restrict__ bc, float* __restrict__ Hent,
                         unsigned* __restrict__ maxH) {
    __shared__ float Wl[HDIM*CDIM];
    __shared__ float bl[CDIM];
    int tid = threadIdx.x;
    for (int idx = tid; idx < HDIM*CDIM; idx += blockDim.x) Wl[idx] = Wc[idx];
    if (tid < CDIM) bl[tid] = bc[tid];
    __syncthreads();

    int i = blockIdx.x * blockDim.x + tid;
    if (i >= NNODES) return;
    const float4* hr = (const float4*)(H + (size_t)i*HDIM);
    float lg[CDIM];
    #pragma unroll
    for (int c = 0; c < CDIM; ++c) lg[c] = bl[c];
    #pragma unroll
    for (int q = 0; q < HDIM/4; ++q) {
        float4 v = hr[q];
        #pragma unroll
        for (int kk = 0; kk < 4; ++kk) {
            float x = (&v.x)[kk];
            int k = q*4 + kk;
            #pragma unroll
            for (int c = 0; c < CDIM; ++c) lg[c] += x * Wl[k*CDIM + c];
        }
    }
    float mx = lg[0];
    #pragma unroll
    for (int c = 1; c < CDIM; ++c) mx = fmaxf(mx, lg[c]);
    float se = 0.f, dot = 0.f;
    #pragma unroll
    for (int c = 0; c < CDIM; ++c) { float e = expf(lg[c]-mx); se += e; dot += e*lg[c]; }
    float lse = mx + logf(se);
    float Hv = lse - dot/se;
    Hv = fmaxf(Hv, 0.f);                 // entropy >= 0; keep uint-bit atomicMax valid
    Hent[i] = Hv;
    atomicMax(maxH, __float_as_uint(Hv));
}

// ---------------- per-graph lambda-weighted pooling + final classify ----------------
__global__ void pool_final(const float* __restrict__ H, const float* __restrict__ Hent,
                           const unsigned* __restrict__ maxH, const int* __restrict__ n2g,
                           const float* __restrict__ Wc, const float* __restrict__ bc,
                           float* __restrict__ out) {
    __shared__ float partial[4][HDIM];
    __shared__ float pooled[HDIM];
    int g = blockIdx.x;
    int w = threadIdx.x >> 6, lane = threadIdx.x & 63;

    int lo = 0, hi = NNODES;
    while (lo < hi) { int mid = (lo+hi) >> 1; if (n2g[mid] < g) lo = mid+1; else hi = mid; }
    int start = lo;
    hi = NNODES;
    while (lo < hi) { int mid = (lo+hi) >> 1; if (n2g[mid] < g+1) lo = mid+1; else hi = mid; }
    int end = lo;

    float invMax = 1.0f / __uint_as_float(*maxH);
    float acc = 0.f;
    for (int i = start + w; i < end; i += 4) {
        float lam = 1.0f - Hent[i] * invMax;
        acc += lam * H[(size_t)i*HDIM + lane];
    }
    partial[w][lane] = acc;
    __syncthreads();
    if (w == 0)
        pooled[lane] = partial[0][lane] + partial[1][lane] + partial[2][lane] + partial[3][lane];
    __syncthreads();
    if (threadIdx.x < CDIM) {
        int c = threadIdx.x;
        float s = bc[c];
        for (int k = 0; k < HDIM; ++k) s += pooled[k] * Wc[k*CDIM + c];
        out[g*CDIM + c] = s;
    }
}

extern "C" void kernel_launch(void* const* d_in, const int* in_sizes, int n_in,
                              void* d_out, int out_size, void* d_ws, size_t ws_size,
                              hipStream_t stream) {
    const float* feat  = (const float*)d_in[0];
    const int*   src   = (const int*)d_in[1];
    const int*   dst   = (const int*)d_in[2];
    const int*   n2g   = (const int*)d_in[3];
    const float* Ws    = (const float*)d_in[4];
    const float* bs    = (const float*)d_in[5];
    const float* gam   = (const float*)d_in[6];
    const float* bet   = (const float*)d_in[7];
    const float* mea   = (const float*)d_in[8];
    const float* var_  = (const float*)d_in[9];
    const float* Wc    = (const float*)d_in[10];
    const float* bc    = (const float*)d_in[11];
    float* out = (float*)d_out;

    char* ws = (char*)d_ws;
    size_t off = 0;
    auto take = [&](size_t bytes) {
        char* p = ws + off;
        off += (bytes + 255) & ~(size_t)255;
        return p;
    };

    unsigned* cnt    = (unsigned*)take((size_t)NNODES*4);
    unsigned* ovfcnt = (unsigned*)take(4);
    int*      ovf    = (int*)take((size_t)OVFCAP*2*4);
    unsigned* maxH   = (unsigned*)take(4);
    float*    M      = (float*)take((size_t)NNODES*HDIM*4);
    float*    Hbuf   = (float*)take((size_t)NNODES*HDIM*4);
    float*    Hent   = (float*)take((size_t)NNODES*4);
    size_t base_need = off;
    int*      csr    = (int*)take((size_t)NNODES*CAP*4);
    size_t csr_need = off;

    bool use_csr = (ws_size >= csr_need);

    hipMemsetAsync(maxH, 0, 4, stream);

    if (use_csr) {
        hipMemsetAsync(cnt, 0, (size_t)NNODES*4, stream);
        hipMemsetAsync(ovfcnt, 0, 4, stream);
        fill_buckets<<<(NEDGES+255)/256, 256, 0, stream>>>(src, dst, cnt, csr, ovfcnt, ovf);
        const float* hin = feat;
        for (int l = 0; l < NLAYERS; ++l) {
            aggregate<<<NNODES/4, 256, 0, stream>>>(hin, cnt, csr, M);
            ovf_add<<<1, 256, 0, stream>>>(hin, ovfcnt, ovf, M);
            transform<<<NNODES/4, 256, 0, stream>>>(M, Hbuf, Ws, bs, gam, bet, mea, var_, l);
            hin = Hbuf;
        }
    } else if (ws_size >= base_need) {
        const float* hin = feat;
        for (int l = 0; l < NLAYERS; ++l) {
            hipMemsetAsync(M, 0, (size_t)NNODES*HDIM*4, stream);
            long long tot = (long long)NEDGES * HDIM;
            scatter_atomic<<<(unsigned)((tot + 255)/256), 256, 0, stream>>>(hin, src, dst, M);
            transform<<<NNODES/4, 256, 0, stream>>>(M, Hbuf, Ws, bs, gam, bet, mea, var_, l);
            hin = Hbuf;
        }
    }

    classify<<<(NNODES+255)/256, 256, 0, stream>>>(Hbuf, Wc, bc, Hent, maxH);
    pool_final<<<NGRAPH, 256, 0, stream>>>(Hbuf, Hent, maxH, n2g, Wc, bc, out);
}